// Round 4
// baseline (577.200 us; speedup 1.0000x reference)
//
#include <hip/hip_runtime.h>
#include <hip/hip_bf16.h>
#include <stdint.h>

#define IN_F 4096
#define OUT_F 4096
#define MTOK 8192
#define TOPX_N 10
#define NUMVALS 200000
#define CSR_BLOCKS ((NUMVALS + 255) / 256)

typedef __bf16 bf16x8 __attribute__((ext_vector_type(8)));
typedef float f32x4 __attribute__((ext_vector_type(4)));

__device__ __forceinline__ void gld_lds16(const void* g, void* l) {
    __builtin_amdgcn_global_load_lds((const __attribute__((address_space(1))) void*)g,
                                     (__attribute__((address_space(3))) void*)l, 16, 0, 0);
}

// ---------------------------------------------------------------------------
// 1) Dequant: W^T[j][k] = lut[j][code(k,j)], bf16, layout (OUT_F, IN_F).
// ---------------------------------------------------------------------------
__global__ __launch_bounds__(256) void k_dequant(const int* __restrict__ qw,
                                                 const float* __restrict__ lut,
                                                 __bf16* __restrict__ Wt) {
    __shared__ int qs[64 * 65];
    __shared__ float ls[64 * 16];
    const int b = blockIdx.x;
    const int jc = (b & 63) * 64;
    const int wc = (b >> 6) * 64;
    const int t = threadIdx.x;

    {
        float4 v = *(const float4*)(lut + (size_t)(jc + (t >> 2)) * 16 + (t & 3) * 4);
        *(float4*)(ls + (t >> 2) * 16 + (t & 3) * 4) = v;
    }
#pragma unroll
    for (int p = 0; p < 4; ++p) {
        int idx = t + p * 256;
        int row = idx >> 4;
        int c4 = (idx & 15) * 4;
        int4 v = *(const int4*)(qw + (size_t)(wc + row) * OUT_F + jc + c4);
        int base = row * 65 + c4;
        qs[base] = v.x; qs[base + 1] = v.y; qs[base + 2] = v.z; qs[base + 3] = v.w;
    }
    __syncthreads();

    const int wave = t >> 6, lane = t & 63;
#pragma unroll
    for (int i = 0; i < 16; ++i) {
        const int c = wave * 16 + i;
        const unsigned q = (unsigned)qs[lane * 65 + c];
        const float* lp = ls + c * 16;
        bf16x8 v;
#pragma unroll
        for (int e = 0; e < 8; ++e) v[e] = (__bf16)lp[(q >> (4 * e)) & 15];
        *(bf16x8*)(Wt + (size_t)(jc + c) * IN_F + (size_t)(wc + lane) * 8) = v;
    }
}

// ---------------------------------------------------------------------------
// 2) CSR outliers + topX dense rows, fused into one launch. Both use exact
//    word-level CAS (adds commute; bf16 rounding-order noise << tolerance).
// ---------------------------------------------------------------------------
__device__ __forceinline__ void bf16_cas_add(__bf16* Wt, size_t elem, float v) {
    unsigned* wp = (unsigned*)Wt + (elem >> 1);
    unsigned sh = (unsigned)(elem & 1) * 16;
    unsigned old = *wp, assumed;
    do {
        assumed = old;
        union { unsigned u; float f; } cv;
        cv.u = ((assumed >> sh) & 0xFFFFu) << 16;      // bf16 -> f32 (exact)
        __bf16 nb = (__bf16)(cv.f + v);
        unsigned nh = *(unsigned short*)&nb;
        unsigned newv = (assumed & ~(0xFFFFu << sh)) | ((unsigned)nh << sh);
        old = atomicCAS(wp, assumed, newv);
    } while (old != assumed);
}

__global__ __launch_bounds__(256) void k_fix(const int* __restrict__ rows,
                                             const int* __restrict__ cols,
                                             const float* __restrict__ vals,
                                             const float* __restrict__ fr,
                                             const int* __restrict__ fri,
                                             __bf16* __restrict__ Wt) {
    const int b = blockIdx.x;
    if (b < CSR_BLOCKS) {
        int n = b * 256 + threadIdx.x;
        if (n >= NUMVALS) return;
        int lo = 0, hi = OUT_F + 1;
        while (lo < hi) {
            int mid = (lo + hi) >> 1;
            if (rows[mid] <= n) lo = mid + 1; else hi = mid;
        }
        int r = lo - 1;
        bf16_cas_add(Wt, (size_t)r * IN_F + cols[n], vals[n]);
    } else {
        int i = (b - CSR_BLOCKS) * 256 + threadIdx.x;
        if (i >= IN_F) return;
#pragma unroll
        for (int t = 0; t < TOPX_N; ++t) {
            int j = fri[t];
            bf16_cas_add(Wt, (size_t)j * IN_F + i, fr[(size_t)i * TOPX_N + t]);
        }
    }
}

// ---------------------------------------------------------------------------
// 3) x fp32 -> bf16
// ---------------------------------------------------------------------------
__global__ void k_cvt(const float* __restrict__ x, __bf16* __restrict__ xb) {
    size_t t = (size_t)blockIdx.x * 256 + threadIdx.x;
    const float4* p = (const float4*)x + 2 * t;
    float4 a = p[0], b = p[1];
    bf16x8 v;
    v[0] = (__bf16)a.x; v[1] = (__bf16)a.y; v[2] = (__bf16)a.z; v[3] = (__bf16)a.w;
    v[4] = (__bf16)b.x; v[5] = (__bf16)b.y; v[6] = (__bf16)b.z; v[7] = (__bf16)b.w;
    ((bf16x8*)xb)[t] = v;
}

// ---------------------------------------------------------------------------
// 4) GEMM: C(8192x4096) = A(8192x4096,bf16) * B^T(4096x4096,bf16) + bias
//    256x256 tile, BK=32, 8 waves (2Mx4N), per-wave 128x64 (8x4 16x16x32).
//    4-BUFFER RING, 2-K-tile monolithic windows:
//      window = { stage next 2 tiles into the 2 bufs not being read ;
//                 compute 2 tiles ; vmcnt(0) ; barrier }
//    1 barrier + 1 vmcnt per 2 K-tiles. The vmcnt(0) drains loads issued at
//    window start, covered by 64 MFMAs of compute. Buffer overwrites are
//    issued after the barrier that follows the last read of the old data.
//    R3 BUG FIXED: 128 K-tiles (IN_F/32) need h = 0..31, not 0..15 (R3
//    summed only half of K -> absmax 6.27 == predicted error of half-sum).
//
//    T2 swizzle (verified 0 conflicts in R1/R2): 16-row x 64B window,
//    16B granule (r,g) at slot P = ((5r+g)&7) + 8g + 32*(r>>3) (bijective;
//    DMA dest is linear lane*16; global source inverse-swizzled; reads
//    swizzled) -> every 16-lane fragment read group is 2-way = free.
// ---------------------------------------------------------------------------
#define ROWB (IN_F * 2)            /* 8192 B per row */
#define MFMA_ __builtin_amdgcn_mfma_f32_16x16x32_bf16

__global__ __launch_bounds__(512, 2) void k_gemm(const __bf16* __restrict__ A,
                                                 const __bf16* __restrict__ Bt,
                                                 const float* __restrict__ bias,
                                                 float* __restrict__ C) {
    __shared__ __align__(1024) char smem[4][32768];   // [buf]{A:16K, B:16K} = 128 KiB

    const int tid = threadIdx.x;
    const int wv = tid >> 6, l = tid & 63;
    const int wm = wv >> 2, wn = wv & 3;

    // XCD-aware swizzle: 512 blocks, 8 XCDs, 64 contiguous per XCD.
    const int bid = blockIdx.x;
    const int swz = (bid & 7) * 64 + (bid >> 3);
    const int n0 = (swz & 15) * 256;
    const int m0 = (swz >> 4) * 256;

    // ---- staging map: lane -> (row rloc, granule gq) living at slot lane ----
    const int q = l & 7, gq = (l >> 3) & 3, rh = l >> 5;
    const int rloc = ((5 * (q - gq + 8)) & 7) + 8 * rh;  // 0..15
    const char* gA  = (const char*)A  + (size_t)(m0 + wv * 32 + rloc) * ROWB + gq * 16;
    const char* gB  = (const char*)Bt + (size_t)(n0 + wv * 32 + rloc) * ROWB + gq * 16;
    const char* gA2 = gA + 16 * ROWB;
    const char* gB2 = gB + 16 * ROWB;
    const int lo = wv * 2048 + l * 16;     // linear DMA dest (A region; B at +16384)

#define STAGE_TILE(bi, koff) do {                                   \
        gld_lds16(gA  + (koff), (char*)smem[bi] + lo);              \
        gld_lds16(gA2 + (koff), (char*)smem[bi] + lo + 1024);       \
        gld_lds16(gB  + (koff), (char*)smem[bi] + 16384 + lo);      \
        gld_lds16(gB2 + (koff), (char*)smem[bi] + 16384 + lo + 1024);\
    } while (0)

    // ---- read map (swizzled): frag row = base + lrow, k-granule kk ----
    const int lrow = l & 15, kk = l >> 4;
    const int rdc = ((5 * lrow + kk) & 7) * 16 + kk * 128 + (lrow >> 3) * 512;
    const int rdA = wm * 8192 + rdc;               // + m*1024
    const int rdB = 16384 + wn * 4096 + rdc;       // + n*1024

    f32x4 acc[8][4] = {};

#define COMPUTE(bi) do {                                                         \
        bf16x8 bfr[4], af[8];                                                    \
        _Pragma("unroll") for (int n = 0; n < 4; ++n)                            \
            bfr[n] = *(const bf16x8*)((const char*)smem[bi] + rdB + n * 1024);   \
        _Pragma("unroll") for (int m = 0; m < 8; ++m)                            \
            af[m] = *(const bf16x8*)((const char*)smem[bi] + rdA + m * 1024);    \
        __builtin_amdgcn_s_setprio(1);                                           \
        _Pragma("unroll") for (int m = 0; m < 8; ++m)                            \
            _Pragma("unroll") for (int n = 0; n < 4; ++n)                        \
                acc[m][n] = MFMA_(af[m], bfr[n], acc[m][n], 0, 0, 0);            \
        __builtin_amdgcn_s_setprio(0);                                           \
    } while (0)

#define WINSYNC do {                                      \
        asm volatile("s_waitcnt vmcnt(0)" ::: "memory");  \
        __builtin_amdgcn_s_barrier();                     \
        asm volatile("" ::: "memory");                    \
    } while (0)

    // ---- prologue: tiles 0,1 -> bufs 0,1 ----
    STAGE_TILE(0, 0);
    STAGE_TILE(1, 64);
    WINSYNC;

    // 128 K-tiles total, 4 per iteration -> 32 iterations.
    for (int h = 0; h < 32; ++h) {
        // window A: stage tiles 4h+2,4h+3 -> bufs 2,3; compute 4h,4h+1
        STAGE_TILE(2, 128);
        STAGE_TILE(3, 192);
        COMPUTE(0);
        COMPUTE(1);
        WINSYNC;
        // window B: stage tiles 4h+4,4h+5 -> bufs 0,1 (h<31); compute 4h+2,4h+3
        if (h < 31) {
            STAGE_TILE(0, 256);
            STAGE_TILE(1, 320);
        }
        COMPUTE(2);
        COMPUTE(3);
        WINSYNC;
        gA += 256; gA2 += 256; gB += 256; gB2 += 256;
    }

    // ---- epilogue: C/D layout col = lane&15, row = (lane>>4)*4 + r ----
    const int m0w = m0 + wm * 128;
    const int n0w = n0 + wn * 64;
#pragma unroll
    for (int n = 0; n < 4; ++n) {
        const int col = n0w + n * 16 + lrow;
        const float bj = bias[col];
#pragma unroll
        for (int m = 0; m < 8; ++m) {
            const int row = m0w + m * 16 + kk * 4;
#pragma unroll
            for (int r = 0; r < 4; ++r)
                C[(size_t)(row + r) * OUT_F + col] = acc[m][n][r] + bj;
        }
    }
#undef STAGE_TILE
#undef COMPUTE
#undef WINSYNC
}

extern "C" void kernel_launch(void* const* d_in, const int* in_sizes, int n_in,
                              void* d_out, int out_size, void* d_ws, size_t ws_size,
                              hipStream_t stream) {
    const float* x         = (const float*)d_in[0];
    const int*   qweight   = (const int*)d_in[1];
    const float* lut       = (const float*)d_in[2];
    const float* bias      = (const float*)d_in[3];
    const int*   rows      = (const int*)d_in[4];
    const int*   cols      = (const int*)d_in[5];
    const float* vals      = (const float*)d_in[6];
    const float* full_rows = (const float*)d_in[7];
    const int*   fri       = (const int*)d_in[8];
    float* out = (float*)d_out;

    __bf16* Wt = (__bf16*)d_ws;                                        // 32 MB: W^T (OUT_F, IN_F)
    __bf16* xb = (__bf16*)((char*)d_ws + (size_t)OUT_F * IN_F * 2);    // 64 MB: x bf16 (8192, 4096)

    k_dequant<<<dim3(64 * 8), 256, 0, stream>>>(qweight, lut, Wt);
    k_fix<<<dim3(CSR_BLOCKS + IN_F / 256), 256, 0, stream>>>(rows, cols, vals, full_rows, fri, Wt);
    k_cvt<<<dim3((size_t)MTOK * IN_F / 8 / 256), 256, 0, stream>>>(x, xb);
    k_gemm<<<dim3((OUT_F / 256) * (MTOK / 256)), 512, 0, stream>>>(xb, Wt, bias, out);
}

// Round 5
// 530.880 us; speedup vs baseline: 1.0873x; 1.0873x over previous
//
#include <hip/hip_runtime.h>
#include <hip/hip_bf16.h>
#include <stdint.h>

#define IN_F 4096
#define OUT_F 4096
#define MTOK 8192
#define TOPX_N 10
#define NUMVALS 200000
#define CSR_BLOCKS ((NUMVALS + 255) / 256)
#define CVT_BLOCKS ((MTOK * IN_F / 8) / 256)   /* 16384 */

typedef __bf16 bf16x8 __attribute__((ext_vector_type(8)));
typedef float f32x4 __attribute__((ext_vector_type(4)));

__device__ __forceinline__ void gld_lds16(const void* g, void* l) {
    __builtin_amdgcn_global_load_lds((const __attribute__((address_space(1))) void*)g,
                                     (__attribute__((address_space(3))) void*)l, 16, 0, 0);
}

// ---------------------------------------------------------------------------
// 1) Dequant: W^T[j][k] = lut[j][code(k,j)], bf16, layout (OUT_F, IN_F).
// ---------------------------------------------------------------------------
__global__ __launch_bounds__(256) void k_dequant(const int* __restrict__ qw,
                                                 const float* __restrict__ lut,
                                                 __bf16* __restrict__ Wt) {
    __shared__ int qs[64 * 65];
    __shared__ float ls[64 * 16];
    const int b = blockIdx.x;
    const int jc = (b & 63) * 64;
    const int wc = (b >> 6) * 64;
    const int t = threadIdx.x;

    {
        float4 v = *(const float4*)(lut + (size_t)(jc + (t >> 2)) * 16 + (t & 3) * 4);
        *(float4*)(ls + (t >> 2) * 16 + (t & 3) * 4) = v;
    }
#pragma unroll
    for (int p = 0; p < 4; ++p) {
        int idx = t + p * 256;
        int row = idx >> 4;
        int c4 = (idx & 15) * 4;
        int4 v = *(const int4*)(qw + (size_t)(wc + row) * OUT_F + jc + c4);
        int base = row * 65 + c4;
        qs[base] = v.x; qs[base + 1] = v.y; qs[base + 2] = v.z; qs[base + 3] = v.w;
    }
    __syncthreads();

    const int wave = t >> 6, lane = t & 63;
#pragma unroll
    for (int i = 0; i < 16; ++i) {
        const int c = wave * 16 + i;
        const unsigned q = (unsigned)qs[lane * 65 + c];
        const float* lp = ls + c * 16;
        bf16x8 v;
#pragma unroll
        for (int e = 0; e < 8; ++e) v[e] = (__bf16)lp[(q >> (4 * e)) & 15];
        *(bf16x8*)(Wt + (size_t)(jc + c) * IN_F + (size_t)(wc + lane) * 8) = v;
    }
}

// ---------------------------------------------------------------------------
// 2) Fused prep: x fp32->bf16 convert (16384 blocks, BW-bound, independent)
//    + CSR outliers (782 blocks, latency-bound CAS) + topX (16 blocks).
//    Complementary resource profiles overlap in one dispatch; must launch
//    AFTER k_dequant (fix parts RMW Wt).
// ---------------------------------------------------------------------------
__device__ __forceinline__ void bf16_cas_add(__bf16* Wt, size_t elem, float v) {
    unsigned* wp = (unsigned*)Wt + (elem >> 1);
    unsigned sh = (unsigned)(elem & 1) * 16;
    unsigned old = *wp, assumed;
    do {
        assumed = old;
        union { unsigned u; float f; } cv;
        cv.u = ((assumed >> sh) & 0xFFFFu) << 16;      // bf16 -> f32 (exact)
        __bf16 nb = (__bf16)(cv.f + v);
        unsigned nh = *(unsigned short*)&nb;
        unsigned newv = (assumed & ~(0xFFFFu << sh)) | ((unsigned)nh << sh);
        old = atomicCAS(wp, assumed, newv);
    } while (old != assumed);
}

__global__ __launch_bounds__(256) void k_prep(const float* __restrict__ x,
                                              __bf16* __restrict__ xb,
                                              const int* __restrict__ rows,
                                              const int* __restrict__ cols,
                                              const float* __restrict__ vals,
                                              const float* __restrict__ fr,
                                              const int* __restrict__ fri,
                                              __bf16* __restrict__ Wt) {
    const int b = blockIdx.x;
    if (b < CVT_BLOCKS) {
        size_t t = (size_t)b * 256 + threadIdx.x;
        const float4* p = (const float4*)x + 2 * t;
        float4 a = p[0], c = p[1];
        bf16x8 v;
        v[0] = (__bf16)a.x; v[1] = (__bf16)a.y; v[2] = (__bf16)a.z; v[3] = (__bf16)a.w;
        v[4] = (__bf16)c.x; v[5] = (__bf16)c.y; v[6] = (__bf16)c.z; v[7] = (__bf16)c.w;
        ((bf16x8*)xb)[t] = v;
    } else if (b < CVT_BLOCKS + CSR_BLOCKS) {
        int n = (b - CVT_BLOCKS) * 256 + threadIdx.x;
        if (n >= NUMVALS) return;
        int lo = 0, hi = OUT_F + 1;
        while (lo < hi) {
            int mid = (lo + hi) >> 1;
            if (rows[mid] <= n) lo = mid + 1; else hi = mid;
        }
        int r = lo - 1;
        bf16_cas_add(Wt, (size_t)r * IN_F + cols[n], vals[n]);
    } else {
        int i = (b - CVT_BLOCKS - CSR_BLOCKS) * 256 + threadIdx.x;
        if (i >= IN_F) return;
#pragma unroll
        for (int t = 0; t < TOPX_N; ++t) {
            int j = fri[t];
            bf16_cas_add(Wt, (size_t)j * IN_F + i, fr[(size_t)i * TOPX_N + t]);
        }
    }
}

// ---------------------------------------------------------------------------
// 3) GEMM — EXACT R1 schedule (verified 300 us / 915 TF / 0 conflicts).
//    C(8192x4096) = A(8192x4096,bf16) * B^T(4096x4096,bf16) + bias.
//    256x256 tile, BK=32, 8 waves (2Mx4N), per-wave 128x64 out.
//    TRI-buffered LDS (3 x 32 KB): stage tile t+2 into buf (t+2)%3 while
//    computing tile t from buf t%3 (no WAR window). Counted vmcnt(4) at the
//    tile boundary (tile t+1's 4 loads stay in flight; never drain to 0 in
//    the loop). 1 barrier per K-tile. setprio around the MFMA cluster.
//    R2 (hand-phased barriers) and R4 (2-tile windows + vmcnt(0) drain)
//    both REGRESSED vs this — do not re-coarsen or re-phase without
//    within-probe A/B evidence.
//
//    T2 swizzle (0 conflicts measured): 16-row x 64B window, 16B granule
//    (r,g) at slot P = ((5r+g)&7) + 8g + 32*(r>>3); DMA dest linear
//    (lane*16), global source inverse-swizzled, reads swizzled.
// ---------------------------------------------------------------------------
#define BK_G 32
#define NKT (IN_F / BK_G)          /* 128 K-tiles */
#define TILE_BYTES 16384           /* 256 rows x 64 B */
#define MFMA_ __builtin_amdgcn_mfma_f32_16x16x32_bf16

__global__ __launch_bounds__(512, 2) void k_gemm(const __bf16* __restrict__ A,
                                                 const __bf16* __restrict__ Bt,
                                                 const float* __restrict__ bias,
                                                 float* __restrict__ C) {
    __shared__ __align__(1024) char smem[3][2][TILE_BYTES];   // [buf][A/B][tile] = 96 KiB

    const int tid = threadIdx.x;
    const int wave = tid >> 6, lane = tid & 63;
    const int wm = wave >> 2, wn = wave & 3;

    // XCD-aware swizzle: 512 blocks, 8 XCDs, 64 contiguous per XCD (n-fast).
    const int bid = blockIdx.x;
    const int swz = (bid & 7) * 64 + (bid >> 3);
    const int n0 = (swz & 15) * 256;
    const int m0 = (swz >> 4) * 256;

    // ---- staging map: lane -> (row_local, granule) it must fetch ----
    const int q = lane & 7, g = (lane >> 3) & 3, rh = lane >> 5;
    const int rloc = ((5 * (q - g + 8)) & 7) + 8 * rh;   // 0..15
    const int w0 = wave * 2;                             // this wave's 2 windows

    const char* gA0 = (const char*)(A  + (size_t)(m0 + w0 * 16 + rloc) * IN_F) + g * 16;
    const char* gA1 = gA0 + 16 * IN_F * 2;
    const char* gB0 = (const char*)(Bt + (size_t)(n0 + w0 * 16 + rloc) * IN_F) + g * 16;
    const char* gB1 = gB0 + 16 * IN_F * 2;
    char* lA = (char*)smem[0][0] + w0 * 1024;            // + boff selects buffer
    char* lB = (char*)smem[0][1] + w0 * 1024;

    // ---- read map: frag (row = wbase + m*16 + lrow, granule kk) ----
    const int lrow = lane & 15, kk = lane >> 4;
    const int rdc = ((5 * lrow + kk) & 7) * 16 + kk * 128 + (lrow >> 3) * 512;
    const int rdA = wm * 8192 + rdc;                     // + m*1024 immediate
    const int rdB = wn * 4096 + rdc;                     // + n*1024 immediate

#define STAGE(boff, koff) do {                               \
        gld_lds16(gA0 + (koff), lA + (boff));                \
        gld_lds16(gA1 + (koff), lA + (boff) + 1024);         \
        gld_lds16(gB0 + (koff), lB + (boff));                \
        gld_lds16(gB1 + (koff), lB + (boff) + 1024);         \
    } while (0)

#define COMPUTE(boff) do {                                                                     \
        const char* pA = (const char*)smem[0][0] + (boff) + rdA;                               \
        const char* pB = (const char*)smem[0][1] + (boff) + rdB;                               \
        bf16x8 bfr[4], af0[4], af1[4];                                                         \
        _Pragma("unroll") for (int n = 0; n < 4; ++n) bfr[n] = *(const bf16x8*)(pB + n * 1024);\
        _Pragma("unroll") for (int m = 0; m < 4; ++m) af0[m] = *(const bf16x8*)(pA + m * 1024);\
        _Pragma("unroll") for (int m = 0; m < 4; ++m) af1[m] = *(const bf16x8*)(pA + 4096 + m * 1024);\
        __builtin_amdgcn_s_setprio(1);                                                         \
        _Pragma("unroll") for (int m = 0; m < 4; ++m)                                          \
            _Pragma("unroll") for (int n = 0; n < 4; ++n)                                      \
                acc[m][n] = MFMA_(af0[m], bfr[n], acc[m][n], 0, 0, 0);                         \
        _Pragma("unroll") for (int m = 0; m < 4; ++m)                                          \
            _Pragma("unroll") for (int n = 0; n < 4; ++n)                                      \
                acc[m + 4][n] = MFMA_(af1[m], bfr[n], acc[m + 4][n], 0, 0, 0);                 \
        __builtin_amdgcn_s_setprio(0);                                                         \
    } while (0)

    f32x4 acc[8][4] = {};

    // prologue: tiles 0,1 -> bufs 0,1
    STAGE(0, 0);
    STAGE(32768, 64);

    int cboff = 0, sboff = 65536;
    for (int t = 0; t < NKT - 1; ++t) {
        // tile t landed (only tile t+1's 4 loads may remain in flight)
        asm volatile("s_waitcnt vmcnt(4)" ::: "memory");
        __builtin_amdgcn_s_barrier();
        asm volatile("" ::: "memory");     // keep stage/ds_reads below the barrier
        if (t + 2 < NKT) STAGE(sboff, (t + 2) * 64);
        COMPUTE(cboff);
        cboff = cboff == 65536 ? 0 : cboff + 32768;
        sboff = sboff == 65536 ? 0 : sboff + 32768;
    }
    asm volatile("s_waitcnt vmcnt(0)" ::: "memory");
    __builtin_amdgcn_s_barrier();
    asm volatile("" ::: "memory");
    COMPUTE(cboff);

    // ---- epilogue: C/D layout col = lane&15, row = (lane>>4)*4 + r ----
    const int m0w = m0 + wm * 128;
    const int n0w = n0 + wn * 64;
#pragma unroll
    for (int n = 0; n < 4; ++n) {
        const int col = n0w + n * 16 + lrow;
        const float bj = bias[col];
#pragma unroll
        for (int m = 0; m < 8; ++m) {
            const int row = m0w + m * 16 + kk * 4;
#pragma unroll
            for (int r = 0; r < 4; ++r)
                C[(size_t)(row + r) * OUT_F + col] = acc[m][n][r] + bj;
        }
    }
#undef STAGE
#undef COMPUTE
}

extern "C" void kernel_launch(void* const* d_in, const int* in_sizes, int n_in,
                              void* d_out, int out_size, void* d_ws, size_t ws_size,
                              hipStream_t stream) {
    const float* x         = (const float*)d_in[0];
    const int*   qweight   = (const int*)d_in[1];
    const float* lut       = (const float*)d_in[2];
    const float* bias      = (const float*)d_in[3];
    const int*   rows      = (const int*)d_in[4];
    const int*   cols      = (const int*)d_in[5];
    const float* vals      = (const float*)d_in[6];
    const float* full_rows = (const float*)d_in[7];
    const int*   fri       = (const int*)d_in[8];
    float* out = (float*)d_out;

    __bf16* Wt = (__bf16*)d_ws;                                        // 32 MB: W^T (OUT_F, IN_F)
    __bf16* xb = (__bf16*)((char*)d_ws + (size_t)OUT_F * IN_F * 2);    // 64 MB: x bf16 (8192, 4096)

    k_dequant<<<dim3(64 * 8), 256, 0, stream>>>(qweight, lut, Wt);
    k_prep<<<dim3(CVT_BLOCKS + CSR_BLOCKS + IN_F / 256), 256, 0, stream>>>(
        x, xb, rows, cols, vals, full_rows, fri, Wt);
    k_gemm<<<dim3((OUT_F / 256) * (MTOK / 256)), 512, 0, stream>>>(xb, Wt, bias, out);
}